// Round 1
// baseline (759.032 us; speedup 1.0000x reference)
//
#include <hip/hip_runtime.h>

#define N_DIM 8192
#define EPS 1e-6f

// ---------- bf16 helpers (bit-level, avoids header type quirks) ----------
__device__ __forceinline__ float bflo(unsigned u) { return __uint_as_float(u << 16); }
__device__ __forceinline__ float bfhi(unsigned u) { return __uint_as_float(u & 0xffff0000u); }
__device__ __forceinline__ unsigned f2bf_bits(float f) {
    unsigned u = __float_as_uint(f);
    return (u + 0x7fffu + ((u >> 16) & 1u)) >> 16;   // round-to-nearest-even
}
__device__ __forceinline__ float sigmoidf_fast(float x) {
    return 1.f / (1.f + __expf(-x));
}

// ---------- block reduction: 256 threads -> scalar ----------
__device__ __forceinline__ float block_reduce_256(float acc) {
    #pragma unroll
    for (int off = 32; off > 0; off >>= 1) acc += __shfl_down(acc, off, 64);
    __shared__ float sred[4];
    const int lane = threadIdx.x & 63;
    const int wid  = threadIdx.x >> 6;
    if (lane == 0) sred[wid] = acc;
    __syncthreads();
    return sred[0] + sred[1] + sred[2] + sred[3];
}

// ---------- k_init: B = bf16(sigmoid(logits)+I); fused first row-normalize ----------
// one block per row; 256 threads; 8 elems/thread/iter (two float4 in, one uint4 out)
__global__ __launch_bounds__(256) void k_init(const float* __restrict__ logits,
                                              unsigned short* __restrict__ B,
                                              float* __restrict__ r,
                                              float* __restrict__ cvec) {
    const int row = blockIdx.x;
    const float4* lrow = (const float4*)(logits + (size_t)row * N_DIM);
    uint4* brow = (uint4*)(B + (size_t)row * N_DIM);
    float acc = 0.f;
    #pragma unroll
    for (int it = 0; it < 4; ++it) {
        const int v = it * 256 + (int)threadIdx.x;      // vec8 index, 0..1023
        const float4 x0 = lrow[2 * v];
        const float4 x1 = lrow[2 * v + 1];
        float s[8] = { sigmoidf_fast(x0.x), sigmoidf_fast(x0.y),
                       sigmoidf_fast(x0.z), sigmoidf_fast(x0.w),
                       sigmoidf_fast(x1.x), sigmoidf_fast(x1.y),
                       sigmoidf_fast(x1.z), sigmoidf_fast(x1.w) };
        const int j = v * 8;
        #pragma unroll
        for (int k = 0; k < 8; ++k)
            if (j + k == row) s[k] += 1.f;
        unsigned b[8];
        #pragma unroll
        for (int k = 0; k < 8; ++k) {
            b[k] = f2bf_bits(s[k]);
            acc += __uint_as_float(b[k] << 16);         // sum the ROUNDED values
        }
        brow[v] = make_uint4(b[0] | (b[1] << 16), b[2] | (b[3] << 16),
                             b[4] | (b[5] << 16), b[6] | (b[7] << 16));
    }
    const float t = block_reduce_256(acc);
    if (threadIdx.x == 0) {
        r[row]   = 1.f / (t + EPS);   // r was 1: r' = 1/(t+eps)
        cvec[row] = 1.f;
    }
}

// ---------- k_row: t[i] = sum_j B[i][j]*c[j]; r[i] = r[i]/(r[i]*t+eps) ----------
__global__ __launch_bounds__(256) void k_row(const unsigned short* __restrict__ B,
                                             const float* __restrict__ cvec,
                                             float* __restrict__ r) {
    const int row = blockIdx.x;
    const uint4* brow = (const uint4*)(B + (size_t)row * N_DIM);
    const float4* cv = (const float4*)cvec;
    float acc = 0.f;
    #pragma unroll
    for (int it = 0; it < 4; ++it) {
        const int v = it * 256 + (int)threadIdx.x;      // vec8 index
        const uint4 b = brow[v];
        const float4 c0 = cv[2 * v];
        const float4 c1 = cv[2 * v + 1];
        acc += bflo(b.x) * c0.x + bfhi(b.x) * c0.y
             + bflo(b.y) * c0.z + bfhi(b.y) * c0.w
             + bflo(b.z) * c1.x + bfhi(b.z) * c1.y
             + bflo(b.w) * c1.z + bfhi(b.w) * c1.w;
    }
    const float t = block_reduce_256(acc);
    if (threadIdx.x == 0) {
        const float rv = r[row];
        r[row] = rv / (rv * t + EPS);
    }
}

// ---------- k_col: partial[rb][j] = sum_{i in rb-chunk} B[i][j]*r[i] ----------
// grid 512: 4 col-blocks x 128 row-blocks; each block: 2048 cols x 64 rows
__global__ __launch_bounds__(256) void k_col(const unsigned short* __restrict__ B,
                                             const float* __restrict__ r,
                                             float* __restrict__ partial) {
    const int cb = blockIdx.x & 3;
    const int rb = blockIdx.x >> 2;
    const int col0 = cb * 2048 + (int)threadIdx.x * 8;
    float a[8] = {0.f, 0.f, 0.f, 0.f, 0.f, 0.f, 0.f, 0.f};
    const int i0 = rb * 64;
    for (int i = i0; i < i0 + 64; ++i) {
        const uint4 b = *(const uint4*)(B + (size_t)i * N_DIM + col0);
        const float ri = r[i];
        a[0] += bflo(b.x) * ri; a[1] += bfhi(b.x) * ri;
        a[2] += bflo(b.y) * ri; a[3] += bfhi(b.y) * ri;
        a[4] += bflo(b.z) * ri; a[5] += bfhi(b.z) * ri;
        a[6] += bflo(b.w) * ri; a[7] += bfhi(b.w) * ri;
    }
    float* p = partial + (size_t)rb * N_DIM + col0;
    ((float4*)p)[0] = make_float4(a[0], a[1], a[2], a[3]);
    ((float4*)p)[1] = make_float4(a[4], a[5], a[6], a[7]);
}

// ---------- k_cupd: u[j] = sum_rb partial[rb][j]; c[j] = c[j]/(c[j]*u+eps) ----------
// grid 128 blocks; block handles 64 columns; 4 thread-groups split the 128 rb's
__global__ __launch_bounds__(256) void k_cupd(const float* __restrict__ partial,
                                              float* __restrict__ cvec) {
    __shared__ float s[4][64];
    const int tc = threadIdx.x & 63;
    const int tg = threadIdx.x >> 6;
    const int j = blockIdx.x * 64 + tc;
    float u = 0.f;
    #pragma unroll 4
    for (int rb = tg * 32; rb < tg * 32 + 32; ++rb)
        u += partial[(size_t)rb * N_DIM + j];
    s[tg][tc] = u;
    __syncthreads();
    if (threadIdx.x < 64) {
        const float tot = s[0][tc] + s[1][tc] + s[2][tc] + s[3][tc];
        const float cj = cvec[j];
        cvec[j] = cj / (cj * tot + EPS);
    }
}

// ---------- k_out: out[i][j] = sigmoid_fp32(logits)+I, scaled by r[i]*c[j] ----------
// reads fp32 logits (not bf16 B) so per-element error is ~fp32-exact
__global__ __launch_bounds__(256) void k_out(const float* __restrict__ logits,
                                             const float* __restrict__ r,
                                             const float* __restrict__ cvec,
                                             float* __restrict__ out) {
    const int row = blockIdx.x;
    const float ri = r[row];
    const float4* lrow = (const float4*)(logits + (size_t)row * N_DIM);
    const float4* cv = (const float4*)cvec;
    float4* orow = (float4*)(out + (size_t)row * N_DIM);
    #pragma unroll
    for (int it = 0; it < 8; ++it) {
        const int v = it * 256 + (int)threadIdx.x;      // float4 index, 0..2047
        const float4 x = lrow[v];
        const float4 cc = cv[v];
        const int j = v * 4;
        float s0 = sigmoidf_fast(x.x); if (j     == row) s0 += 1.f;
        float s1 = sigmoidf_fast(x.y); if (j + 1 == row) s1 += 1.f;
        float s2 = sigmoidf_fast(x.z); if (j + 2 == row) s2 += 1.f;
        float s3 = sigmoidf_fast(x.w); if (j + 3 == row) s3 += 1.f;
        orow[v] = make_float4(s0 * ri * cc.x, s1 * ri * cc.y,
                              s2 * ri * cc.z, s3 * ri * cc.w);
    }
}

extern "C" void kernel_launch(void* const* d_in, const int* in_sizes, int n_in,
                              void* d_out, int out_size, void* d_ws, size_t ws_size,
                              hipStream_t stream) {
    const float* logits = (const float*)d_in[0];
    float* out = (float*)d_out;
    // Stash bf16 M0 in the UPPER HALF of d_out (128 MB). It is dead by the time
    // k_out rewrites d_out, and k_out reads only logits/r/c — no aliasing race.
    unsigned short* B = (unsigned short*)(out + (size_t)N_DIM * N_DIM / 2);
    // d_ws: r (32KB) | c (32KB) | partial (128*8192 floats = 4MB)
    float* r      = (float*)d_ws;
    float* cvec   = r + N_DIM;
    float* partial = cvec + N_DIM;

    const dim3 blk(256);
    k_init<<<dim3(N_DIM), blk, 0, stream>>>(logits, B, r, cvec);
    for (int it = 0; it < 5; ++it) {
        if (it > 0) k_row<<<dim3(N_DIM), blk, 0, stream>>>(B, cvec, r);
        k_col<<<dim3(512), blk, 0, stream>>>(B, r, partial);
        k_cupd<<<dim3(128), blk, 0, stream>>>(partial, cvec);
    }
    k_out<<<dim3(N_DIM), blk, 0, stream>>>(logits, r, cvec, out);
}

// Round 2
// 635.581 us; speedup vs baseline: 1.1942x; 1.1942x over previous
//
#include <hip/hip_runtime.h>

#define N_DIM 8192
#define EPS 1e-6f
#define R_STRIP 16                     // rows per fused block
#define NRB (N_DIM / R_STRIP)          // 512 partial row-chunks

// ---------- bf16 helpers (bit-level) ----------
__device__ __forceinline__ float bflo(unsigned u) { return __uint_as_float(u << 16); }
__device__ __forceinline__ float bfhi(unsigned u) { return __uint_as_float(u & 0xffff0000u); }
__device__ __forceinline__ unsigned f2bf_bits(float f) {
    unsigned u = __float_as_uint(f);
    return (u + 0x7fffu + ((u >> 16) & 1u)) >> 16;   // round-to-nearest-even
}
__device__ __forceinline__ float sigmoidf_fast(float x) {
    return 1.f / (1.f + __expf(-x));
}
__device__ __forceinline__ float dot8(uint4 b, float4 c0, float4 c1) {
    return bflo(b.x) * c0.x + bfhi(b.x) * c0.y + bflo(b.y) * c0.z + bfhi(b.y) * c0.w
         + bflo(b.z) * c1.x + bfhi(b.z) * c1.y + bflo(b.w) * c1.z + bfhi(b.w) * c1.w;
}
__device__ __forceinline__ void acc8(float* a, uint4 b, float rr) {
    a[0] += bflo(b.x) * rr; a[1] += bfhi(b.x) * rr;
    a[2] += bflo(b.y) * rr; a[3] += bfhi(b.y) * rr;
    a[4] += bflo(b.z) * rr; a[5] += bfhi(b.z) * rr;
    a[6] += bflo(b.w) * rr; a[7] += bfhi(b.w) * rr;
}
// sigmoid+I, pack 8 to bf16, accumulate rounded sum into t
__device__ __forceinline__ uint4 sig_pack8(float4 x0, float4 x1, int jbase, int row, float& t) {
    float s[8] = { sigmoidf_fast(x0.x), sigmoidf_fast(x0.y), sigmoidf_fast(x0.z), sigmoidf_fast(x0.w),
                   sigmoidf_fast(x1.x), sigmoidf_fast(x1.y), sigmoidf_fast(x1.z), sigmoidf_fast(x1.w) };
    #pragma unroll
    for (int k = 0; k < 8; ++k)
        if (jbase + k == row) s[k] += 1.f;
    unsigned b[8];
    #pragma unroll
    for (int k = 0; k < 8; ++k) {
        b[k] = f2bf_bits(s[k]);
        t += __uint_as_float(b[k] << 16);          // sum the ROUNDED values
    }
    return make_uint4(b[0] | (b[1] << 16), b[2] | (b[3] << 16),
                      b[4] | (b[5] << 16), b[6] | (b[7] << 16));
}

// ---------- k_init: B = bf16(sigmoid+I); fused iteration-1 row norm + col partials ----------
// grid NRB=512 blocks, 16 rows each, 2-row register-cached batches
__global__ __launch_bounds__(256) void k_init(const float* __restrict__ logits,
                                              unsigned short* __restrict__ B,
                                              float* __restrict__ r,
                                              float* __restrict__ partial) {
    __shared__ float sred[2][4];
    const int tid = threadIdx.x;
    const int lane = tid & 63, wid = tid >> 6;
    const int i0 = blockIdx.x * R_STRIP;
    float a[4][8];
    #pragma unroll
    for (int s = 0; s < 4; ++s)
        #pragma unroll
        for (int k = 0; k < 8; ++k) a[s][k] = 0.f;

    for (int bb = 0; bb < R_STRIP / 2; ++bb) {
        const int row0 = i0 + 2 * bb, row1 = row0 + 1;
        const float4* l0 = (const float4*)(logits + (size_t)row0 * N_DIM);
        const float4* l1 = (const float4*)(logits + (size_t)row1 * N_DIM);
        uint4* w0 = (uint4*)(B + (size_t)row0 * N_DIM);
        uint4* w1 = (uint4*)(B + (size_t)row1 * N_DIM);
        uint4 b0[4], b1[4];
        float t0 = 0.f, t1 = 0.f;
        #pragma unroll
        for (int s = 0; s < 4; ++s) {
            const int v = s * 256 + tid;
            b0[s] = sig_pack8(l0[2 * v], l0[2 * v + 1], v * 8, row0, t0);
            b1[s] = sig_pack8(l1[2 * v], l1[2 * v + 1], v * 8, row1, t1);
            w0[v] = b0[s];
            w1[v] = b1[s];
        }
        #pragma unroll
        for (int off = 32; off > 0; off >>= 1) {
            t0 += __shfl_down(t0, off, 64);
            t1 += __shfl_down(t1, off, 64);
        }
        if (lane == 0) { sred[0][wid] = t0; sred[1][wid] = t1; }
        __syncthreads();
        const float T0 = sred[0][0] + sred[0][1] + sred[0][2] + sred[0][3];
        const float T1 = sred[1][0] + sred[1][1] + sred[1][2] + sred[1][3];
        const float r0 = 1.f / (T0 + EPS);         // r_old = 1
        const float r1 = 1.f / (T1 + EPS);
        __syncthreads();                            // sred consumed before next batch overwrites
        if (tid == 0) { r[row0] = r0; r[row1] = r1; }
        #pragma unroll
        for (int s = 0; s < 4; ++s) { acc8(a[s], b0[s], r0); acc8(a[s], b1[s], r1); }
    }
    float* p = partial + (size_t)blockIdx.x * N_DIM;
    #pragma unroll
    for (int s = 0; s < 4; ++s) {
        const int col = s * 2048 + tid * 8;
        *(float4*)(p + col)     = make_float4(a[s][0], a[s][1], a[s][2], a[s][3]);
        *(float4*)(p + col + 4) = make_float4(a[s][4], a[s][5], a[s][6], a[s][7]);
    }
}

// ---------- k_fused: one full iteration's row step + col partials, ONE pass over B ----------
__global__ __launch_bounds__(256) void k_fused(const unsigned short* __restrict__ B,
                                               const float* __restrict__ cvec,
                                               float* __restrict__ r,
                                               float* __restrict__ partial) {
    __shared__ float sred[2][4];
    const int tid = threadIdx.x;
    const int lane = tid & 63, wid = tid >> 6;
    const int i0 = blockIdx.x * R_STRIP;
    const float4* cv = (const float4*)cvec;
    float a[4][8];
    #pragma unroll
    for (int s = 0; s < 4; ++s)
        #pragma unroll
        for (int k = 0; k < 8; ++k) a[s][k] = 0.f;

    for (int bb = 0; bb < R_STRIP / 2; ++bb) {
        const int row0 = i0 + 2 * bb, row1 = row0 + 1;
        const float r0old = r[row0];
        const float r1old = r[row1];
        const uint4* br0 = (const uint4*)(B + (size_t)row0 * N_DIM);
        const uint4* br1 = (const uint4*)(B + (size_t)row1 * N_DIM);
        uint4 b0[4], b1[4];
        float t0 = 0.f, t1 = 0.f;
        #pragma unroll
        for (int s = 0; s < 4; ++s) {
            const int v = s * 256 + tid;
            b0[s] = br0[v];
            b1[s] = br1[v];
            const float4 c0 = cv[2 * v];
            const float4 c1 = cv[2 * v + 1];
            t0 += dot8(b0[s], c0, c1);
            t1 += dot8(b1[s], c0, c1);
        }
        #pragma unroll
        for (int off = 32; off > 0; off >>= 1) {
            t0 += __shfl_down(t0, off, 64);
            t1 += __shfl_down(t1, off, 64);
        }
        if (lane == 0) { sred[0][wid] = t0; sred[1][wid] = t1; }
        __syncthreads();
        const float T0 = sred[0][0] + sred[0][1] + sred[0][2] + sred[0][3];
        const float T1 = sred[1][0] + sred[1][1] + sred[1][2] + sred[1][3];
        const float r0 = r0old / (r0old * T0 + EPS);
        const float r1 = r1old / (r1old * T1 + EPS);
        __syncthreads();                            // all sred + r_old reads done
        if (tid == 0) { r[row0] = r0; r[row1] = r1; }
        #pragma unroll
        for (int s = 0; s < 4; ++s) { acc8(a[s], b0[s], r0); acc8(a[s], b1[s], r1); }
    }
    float* p = partial + (size_t)blockIdx.x * N_DIM;
    #pragma unroll
    for (int s = 0; s < 4; ++s) {
        const int col = s * 2048 + tid * 8;
        *(float4*)(p + col)     = make_float4(a[s][0], a[s][1], a[s][2], a[s][3]);
        *(float4*)(p + col + 4) = make_float4(a[s][4], a[s][5], a[s][6], a[s][7]);
    }
}

// ---------- k_cupd: u[j] = sum over NRB partials; c update (first=1: c_old=1) ----------
__global__ __launch_bounds__(256) void k_cupd(const float* __restrict__ partial,
                                              float* __restrict__ cvec, int first) {
    __shared__ float s[4][64];
    const int tc = threadIdx.x & 63;
    const int tg = threadIdx.x >> 6;
    const int j = blockIdx.x * 64 + tc;             // grid 128
    float u = 0.f;
    #pragma unroll 8
    for (int rb = tg * (NRB / 4); rb < (tg + 1) * (NRB / 4); ++rb)
        u += partial[(size_t)rb * N_DIM + j];
    s[tg][tc] = u;
    __syncthreads();
    if (threadIdx.x < 64) {
        const float tot = s[0][tc] + s[1][tc] + s[2][tc] + s[3][tc];
        const float cj = first ? 1.f : cvec[j];
        cvec[j] = cj / (cj * tot + EPS);
    }
}

// ---------- k_out: out[i][j] = bf16(B)[i][j] * r[i] * c[j] ----------
__global__ __launch_bounds__(256) void k_out(const unsigned short* __restrict__ B,
                                             const float* __restrict__ r,
                                             const float* __restrict__ cvec,
                                             float* __restrict__ out) {
    const int row = blockIdx.x;
    const float ri = r[row];
    const uint4* brow = (const uint4*)(B + (size_t)row * N_DIM);
    const float4* cv = (const float4*)cvec;
    float* orow = out + (size_t)row * N_DIM;
    #pragma unroll
    for (int it = 0; it < 4; ++it) {
        const int v = it * 256 + (int)threadIdx.x;
        const uint4 b = brow[v];
        const float4 c0 = cv[2 * v];
        const float4 c1 = cv[2 * v + 1];
        *(float4*)(orow + v * 8)     = make_float4(bflo(b.x) * ri * c0.x, bfhi(b.x) * ri * c0.y,
                                                   bflo(b.y) * ri * c0.z, bfhi(b.y) * ri * c0.w);
        *(float4*)(orow + v * 8 + 4) = make_float4(bflo(b.z) * ri * c1.x, bfhi(b.z) * ri * c1.y,
                                                   bflo(b.w) * ri * c1.z, bfhi(b.w) * ri * c1.w);
    }
}

// ---------- fallback k_out reading fp32 logits (used only if ws too small for B) ----------
__global__ __launch_bounds__(256) void k_out_logits(const float* __restrict__ logits,
                                                    const float* __restrict__ r,
                                                    const float* __restrict__ cvec,
                                                    float* __restrict__ out) {
    const int row = blockIdx.x;
    const float ri = r[row];
    const float4* lrow = (const float4*)(logits + (size_t)row * N_DIM);
    const float4* cv = (const float4*)cvec;
    float4* orow = (float4*)(out + (size_t)row * N_DIM);
    #pragma unroll
    for (int it = 0; it < 8; ++it) {
        const int v = it * 256 + (int)threadIdx.x;
        const float4 x = lrow[v];
        const float4 cc = cv[v];
        const int j = v * 4;
        float s0 = sigmoidf_fast(x.x); if (j     == row) s0 += 1.f;
        float s1 = sigmoidf_fast(x.y); if (j + 1 == row) s1 += 1.f;
        float s2 = sigmoidf_fast(x.z); if (j + 2 == row) s2 += 1.f;
        float s3 = sigmoidf_fast(x.w); if (j + 3 == row) s3 += 1.f;
        orow[v] = make_float4(s0 * ri * cc.x, s1 * ri * cc.y, s2 * ri * cc.z, s3 * ri * cc.w);
    }
}

extern "C" void kernel_launch(void* const* d_in, const int* in_sizes, int n_in,
                              void* d_out, int out_size, void* d_ws, size_t ws_size,
                              hipStream_t stream) {
    const float* logits = (const float*)d_in[0];
    float* out = (float*)d_out;
    const size_t nn = (size_t)N_DIM * N_DIM;
    // ws layout: B (128 MB bf16) | r | c | partial (NRB*N floats = 16 MB)
    const size_t need = nn * 2 + (2 * N_DIM + (size_t)NRB * N_DIM) * 4;
    const bool use_ws = ws_size >= need + 256;
    float* wsf = (float*)d_ws;
    unsigned short* B;
    float *r, *cvec, *partial;
    if (use_ws) {                                   // ws is 1 GiB in this harness
        B = (unsigned short*)wsf;
        r = wsf + nn / 2;
    } else {                                        // stash B in upper half of d_out
        B = (unsigned short*)(out + nn / 2);
        r = wsf;
    }
    cvec = r + N_DIM;
    partial = cvec + N_DIM;

    const dim3 blk(256);
    k_init<<<dim3(NRB), blk, 0, stream>>>(logits, B, r, partial);
    k_cupd<<<dim3(128), blk, 0, stream>>>(partial, cvec, 1);
    for (int it = 1; it < 5; ++it) {
        k_fused<<<dim3(NRB), blk, 0, stream>>>(B, cvec, r, partial);
        k_cupd<<<dim3(128), blk, 0, stream>>>(partial, cvec, 0);
    }
    if (use_ws)
        k_out<<<dim3(N_DIM), blk, 0, stream>>>(B, r, cvec, out);
    else
        k_out_logits<<<dim3(N_DIM), blk, 0, stream>>>(logits, r, cvec, out);
}